// Round 5
// baseline (215.026 us; speedup 1.0000x reference)
//
#include <hip/hip_runtime.h>

typedef _Float16 f16;
typedef __fp16 h16x2 __attribute__((ext_vector_type(2)));
typedef _Float16 f16x8 __attribute__((ext_vector_type(8)));
typedef float f32x4 __attribute__((ext_vector_type(4)));

#define H_ 12
#define B_ 4
#define S_ 2048
#define DM 768
#define DK 64
#define HBSD ((size_t)H_ * B_ * S_ * DK)

__device__ __forceinline__ f16 f2h(float f) { return (f16)f; }
__device__ __forceinline__ float max3f(float a, float b, float c) {
  return fmaxf(fmaxf(a, b), c);  // clang fuses to v_max3_f32
}

// async global->LDS, 16B per lane. LDS dest must be wave-uniform base + lane*16.
__device__ __forceinline__ void gl_lds16(const f16* g, f16* l) {
  __builtin_amdgcn_global_load_lds(
      (const __attribute__((address_space(1))) void*)g,
      (__attribute__((address_space(3))) void*)l, 16, 0, 0);
}

// ---------------- prep kernels ----------------

__global__ __launch_bounds__(256) void cast_x_kernel(const float* __restrict__ x,
                                                     f16* __restrict__ xb, int n4) {
  int i = blockIdx.x * 256 + threadIdx.x;
  if (i < n4) {
    float4 v = ((const float4*)x)[i];
    union { f16 h[4]; uint2 u; } pk;
    pk.h[0] = f2h(v.x); pk.h[1] = f2h(v.y); pk.h[2] = f2h(v.z); pk.h[3] = f2h(v.w);
    ((uint2*)xb)[i] = pk.u;
  }
}

// W_{which}[h][m][c] -> Wt[(which*768 + h*64 + c)][m]  (coalesced LDS transpose)
__global__ __launch_bounds__(256) void tcast_qkv_kernel(const float* __restrict__ WQ,
                                                        const float* __restrict__ WK,
                                                        const float* __restrict__ WV,
                                                        f16* __restrict__ Wt) {
  __shared__ float L[64][65];
  const int m0 = blockIdx.x * 64, which = blockIdx.y, h = blockIdx.z;
  const float* in = (which == 0 ? WQ : which == 1 ? WK : WV) + (size_t)h * DM * DK;
  const int t = threadIdx.x;
  const int lr = t >> 2, lc = (t & 3) * 16;
  const float* ip = in + (size_t)(m0 + lr) * DK + lc;
#pragma unroll
  for (int i = 0; i < 4; i++) {
    float4 v = *(const float4*)(ip + i * 4);
    L[lr][lc + i * 4 + 0] = v.x;
    L[lr][lc + i * 4 + 1] = v.y;
    L[lr][lc + i * 4 + 2] = v.z;
    L[lr][lc + i * 4 + 3] = v.w;
  }
  __syncthreads();
  const int oc = t >> 2, om = (t & 3) * 16;
  union { f16 hh[16]; uint4 u[2]; } pk;
#pragma unroll
  for (int jx = 0; jx < 16; jx++) pk.hh[jx] = f2h(L[om + jx][oc]);
  f16* op = Wt + ((size_t)which * DM + h * DK + oc) * DM + m0 + om;
  *(uint4*)op = pk.u[0];
  *(uint4*)(op + 8) = pk.u[1];
}

// WO[n][d] -> Wot[d][n]
__global__ __launch_bounds__(256) void tcast_wo_kernel(const float* __restrict__ WO,
                                                       f16* __restrict__ Wt) {
  __shared__ float L[64][65];
  const int n0 = blockIdx.x * 64, d0 = blockIdx.y * 64;
  const int t = threadIdx.x;
  const int lr = t >> 2, lc = (t & 3) * 16;
  const float* ip = WO + (size_t)(n0 + lr) * DM + d0 + lc;
#pragma unroll
  for (int i = 0; i < 4; i++) {
    float4 v = *(const float4*)(ip + i * 4);
    L[lr][lc + i * 4 + 0] = v.x;
    L[lr][lc + i * 4 + 1] = v.y;
    L[lr][lc + i * 4 + 2] = v.z;
    L[lr][lc + i * 4 + 3] = v.w;
  }
  __syncthreads();
  const int oc = t >> 2, om = (t & 3) * 16;
  union { f16 hh[16]; uint4 u[2]; } pk;
#pragma unroll
  for (int jx = 0; jx < 16; jx++) pk.hh[jx] = f2h(L[om + jx][oc]);
  f16* op = Wt + (size_t)(d0 + oc) * DM + n0 + om;
  *(uint4*)op = pk.u[0];
  *(uint4*)(op + 8) = pk.u[1];
}

// ---------------- GEMM, BK=64 2-slab: C[M,N] = A[M,K] * Bt[N,K]^T ----------------
// LDS layout per matrix: [slab s][row 128][32 cols]; slab stride 128*32 = 4096.
// Bank-conflict fix: XOR-swizzle byte bits 4-5 with row bits 1-2 (source-pre-swizzle
// + swizzled read quad qsw).
// XCD swizzle (T1): each XCD gets a contiguous chunk of the linear grid so A-row
// panels stay resident in its private L2 (nwg % 8 == 0 for both launches).
// Q outputs (MODE==1, which==0) are pre-scaled by log2(e)/8 so the flash kernel's
// QK^T scores come out directly in log2 units (scale applied to f32 acc BEFORE the
// single f16 round — numerically identical to scaling in flash).
template <int MODE>
__global__ __launch_bounds__(256) void gemm_bt_kernel(const f16* __restrict__ A,
                                                      const f16* __restrict__ Bt,
                                                      float* __restrict__ Cf,
                                                      f16* __restrict__ Cq,
                                                      f16* __restrict__ Vt, int N) {
  constexpr int K = 768;
  __shared__ __align__(16) f16 As[2 * 128 * 32];
  __shared__ __align__(16) f16 Bs[2 * 128 * 32];
  const int t = threadIdx.x;
  const int nbx = gridDim.x, nwg = nbx * gridDim.y;
  const int d = blockIdx.y * nbx + blockIdx.x;
  const int wg = (d & 7) * (nwg >> 3) + (d >> 3);  // bijective (nwg%8==0)
  const int m0 = (wg / nbx) * 128, n0 = (wg % nbx) * 128;
  const int lane = t & 63, wave = t >> 6;
  const int l15 = lane & 15, quad = lane >> 4;
  const int qsw = quad ^ ((l15 >> 1) & 3);  // swizzled read quad
  const int m_off = (wave & 1) * 64, n_off = (wave >> 1) * 64;
  const int r0 = t >> 2, ko = ((t & 3) ^ ((t >> 3) & 3)) * 8;  // swizzled source col
  const f16* Ag0 = A + (size_t)(m0 + r0) * K + ko;
  const f16* Ag1 = A + (size_t)(m0 + r0 + 64) * K + ko;
  const f16* Bg0 = Bt + (size_t)(n0 + r0) * K + ko;
  const f16* Bg1 = Bt + (size_t)(n0 + r0 + 64) * K + ko;

  f32x4 acc[4][4];
  const f32x4 z4 = {0.f, 0.f, 0.f, 0.f};
  for (int i = 0; i < 4; i++)
    for (int j = 0; j < 4; j++) acc[i][j] = z4;

  for (int kt = 0; kt < K; kt += 64) {
    __syncthreads();
#pragma unroll
    for (int s = 0; s < 2; s++) {
      gl_lds16(Ag0 + kt + s * 32, &As[s * 4096 + t * 8]);
      gl_lds16(Ag1 + kt + s * 32, &As[s * 4096 + 2048 + t * 8]);
      gl_lds16(Bg0 + kt + s * 32, &Bs[s * 4096 + t * 8]);
      gl_lds16(Bg1 + kt + s * 32, &Bs[s * 4096 + 2048 + t * 8]);
    }
    __syncthreads();
#pragma unroll
    for (int s = 0; s < 2; s++) {
      f16x8 af[4], bfr[4];
#pragma unroll
      for (int i = 0; i < 4; i++)
        af[i] = *(const f16x8*)&As[s * 4096 + (m_off + i * 16 + l15) * 32 + qsw * 8];
#pragma unroll
      for (int i = 0; i < 4; i++)
        bfr[i] = *(const f16x8*)&Bs[s * 4096 + (n_off + i * 16 + l15) * 32 + qsw * 8];
#pragma unroll
      for (int mi = 0; mi < 4; mi++)
#pragma unroll
        for (int ni = 0; ni < 4; ni++)
          acc[mi][ni] = __builtin_amdgcn_mfma_f32_16x16x32_f16(af[mi], bfr[ni],
                                                               acc[mi][ni], 0, 0, 0);
    }
  }

  if (MODE == 0) {
#pragma unroll
    for (int mi = 0; mi < 4; mi++) {
      int row = m0 + m_off + mi * 16 + quad * 4;
#pragma unroll
      for (int ni = 0; ni < 4; ni++) {
        int col = n0 + n_off + ni * 16 + l15;
#pragma unroll
        for (int r = 0; r < 4; r++) Cf[(size_t)(row + r) * N + col] = acc[mi][ni][r];
      }
    }
  } else {
#pragma unroll
    for (int mi = 0; mi < 4; mi++) {
      int srow = m0 + m_off + mi * 16 + quad * 4;
      int bb = srow >> 11, ss = srow & 2047;
#pragma unroll
      for (int ni = 0; ni < 4; ni++) {
        int n = n0 + n_off + ni * 16 + l15;
        int which = n / DM;
        int rr = n - which * DM;
        int h = rr >> 6, kk = rr & 63;
        if (which < 2) {  // Q,K -> [h][b][s][64]; Q pre-scaled by log2(e)/8
          float scl = (which == 0) ? 0.18033688011f : 1.0f;
#pragma unroll
          for (int r = 0; r < 4; r++) {
            size_t dst = (size_t)which * HBSD +
                         ((size_t)((h * B_ + bb) * S_) + ss + r) * DK + kk;
            Cq[dst] = f2h(acc[mi][ni][r] * scl);
          }
        } else {  // V -> Vt [h][b][d][s]
          union { f16 hh[4]; uint2 u; } pk;
#pragma unroll
          for (int r = 0; r < 4; r++) pk.hh[r] = f2h(acc[mi][ni][r]);
          *(uint2*)&Vt[((size_t)(h * B_ + bb) * DK + kk) * S_ + ss] = pk.u;
        }
      }
    }
  }
}

// ---------------- flash attention v11: v10 + shfl-free softmax fast path --------
// 768 blocks; bid&7 = XCD; block owns q-tiles qbA=pr, qbB=31-pr of (h,b)=hb —
// 33 job-tiles per block. Pair-staging: 2 kv-tiles per barrier pair.
// v11: Q arrives pre-scaled by log2(e)/8 (GEMM epilogue) so scores are directly
// in log2 units; defer-max check is PER-LANE (no shfls on the fast path; wave-max
// shfls only inside the rare rescale branch — rescale alpha stays row-consistent);
// l partial stays per-lane, cross-quad combine moved to the epilogue.
__global__ __launch_bounds__(256, 3) void flash_kernel(const f16* __restrict__ Qg,
                                                       const f16* __restrict__ Kg,
                                                       const f16* __restrict__ Vtg,
                                                       f16* __restrict__ MH) {
  __shared__ __align__(16) f16 Ksh[2][4096];  // [tile][kc2][kv][32] (swizzled)
  __shared__ __align__(16) f16 Vsh[2][4096];  // [tile][kc2][v][32]  (swizzled)
  __shared__ __align__(16) f16 Ps[4][16 * 72];

  const int t = threadIdx.x, lane = t & 63, w = t >> 6;
  const int l15 = lane & 15, quad = lane >> 4;
  const int qsw = quad ^ ((l15 >> 1) & 3);  // swizzled read quad for Ksh/Vsh
  const int bid = blockIdx.x;
  const int xcd = bid & 7, gi = bid >> 3;
  const int hbi = gi % 6, pr = gi / 6;
  const int hb = xcd * 6 + hbi;
  const int qbA = pr, qbB = 31 - pr;
  const int h = hb >> 2, b = hb & 3;
  const size_t base = (size_t)hb * S_ * DK;
  const f16* Qp = Qg + base;
  const f16* Kp = Kg + base;
  const f16* Vp = Vtg + base;  // [d][S_]

  // Q fragments for both jobs, once from global (already ×log2(e)/8)
  f16x8 aqA[2], aqB[2];
  {
    const f16* qa = Qp + (size_t)(qbA * 64 + w * 16 + l15) * DK + quad * 8;
    aqA[0] = *(const f16x8*)(qa);
    aqA[1] = *(const f16x8*)(qa + 32);
    const f16* qb_ = Qp + (size_t)(qbB * 64 + w * 16 + l15) * DK + quad * 8;
    aqB[0] = *(const f16x8*)(qb_);
    aqB[1] = *(const f16x8*)(qb_ + 32);
  }
  const int qlaneA = qbA * 64 + w * 16 + l15;
  const int qlaneB = qbB * 64 + w * 16 + l15;

  // staging source: pre-swizzled column so linear global_load_lds yields the
  // swizzled LDS layout (both-sides-or-neither).
  const int srow = t >> 2, scol = ((t & 3) ^ ((t >> 3) & 3)) * 8;
  const f16* Kst = Kp + (size_t)srow * DK + scol;
  const f16* Vst = Vp + (size_t)srow * S_ + scol;

  float mA = -1e30f, lA = 0.f, mB = -1e30f, lB = 0.f;  // l is per-lane partial
  f32x4 oA[4], oB[4];
  const f32x4 z4 = {0.f, 0.f, 0.f, 0.f};
#pragma unroll
  for (int ni = 0; ni < 4; ni++) { oA[ni] = z4; oB[ni] = z4; }

  auto stage = [&](int buf, int kv0) {
    gl_lds16(Kst + (size_t)kv0 * DK, &Ksh[buf][t * 8]);
    gl_lds16(Kst + (size_t)kv0 * DK + 32, &Ksh[buf][2048 + t * 8]);
    gl_lds16(Vst + kv0, &Vsh[buf][t * 8]);
    gl_lds16(Vst + kv0 + 32, &Vsh[buf][2048 + t * 8]);
  };

  // per-job tile processing
  auto do_job = [&](int buf, const f16x8* aq, float& m_s, float& l_s, f32x4* oacc,
                    int qlane, int kv0, bool diag) {
    f32x4 sa[4];
#pragma unroll
    for (int mi = 0; mi < 4; mi++) {
      f16x8 k0 = *(const f16x8*)&Ksh[buf][(mi * 16 + l15) * 32 + qsw * 8];
      sa[mi] = __builtin_amdgcn_mfma_f32_16x16x32_f16(k0, aq[0], z4, 0, 0, 0);
    }
#pragma unroll
    for (int mi = 0; mi < 4; mi++) {
      f16x8 k1 = *(const f16x8*)&Ksh[buf][2048 + (mi * 16 + l15) * 32 + qsw * 8];
      sa[mi] = __builtin_amdgcn_mfma_f32_16x16x32_f16(k1, aq[1], sa[mi], 0, 0, 0);
    }

    if (diag) {  // diagonal tile: mask kv > q
#pragma unroll
      for (int mi = 0; mi < 4; mi++)
#pragma unroll
        for (int r = 0; r < 4; r++)
          if (kv0 + mi * 16 + quad * 4 + r > qlane) sa[mi][r] = -1e30f;
    }

    // per-lane max of this lane's 16 score elements (already log2-scaled)
    float g0 = max3f(sa[0][0], sa[0][1], sa[0][2]);
    float g1 = max3f(sa[0][3], sa[1][0], sa[1][1]);
    float g2 = max3f(sa[1][2], sa[1][3], sa[2][0]);
    float g3 = max3f(sa[2][1], sa[2][2], sa[2][3]);
    float g4 = max3f(sa[3][0], sa[3][1], sa[3][2]);
    float mx = fmaxf(max3f(g0, g1, g2), max3f(g3, g4, sa[3][3]));
    // defer-max (T13), per-lane check: fast path needs NO cross-lane reduce.
    // If every lane's local max is within threshold, P <= 2^8 bounded — keep m.
    if (!__all(mx <= m_s + 8.f)) {
      // rare: form the row max (4 quads share a q-row), rescale consistently
      float mr = fmaxf(mx, __shfl_xor(mx, 16));
      mr = fmaxf(mr, __shfl_xor(mr, 32));
      float m2 = fmaxf(m_s, mr);
      float alpha = __builtin_exp2f(m_s - m2);
      l_s *= alpha;
#pragma unroll
      for (int ni = 0; ni < 4; ni++)
#pragma unroll
        for (int r = 0; r < 4; r++) oacc[ni][r] *= alpha;
      m_s = m2;
    }
    const float m2 = m_s;
    float rs = 0.f;
#pragma unroll
    for (int mi = 0; mi < 4; mi++)
#pragma unroll
      for (int r = 0; r < 4; r++) {
        float p = __builtin_exp2f(sa[mi][r] - m2);
        sa[mi][r] = p;
        rs += p;
      }
    l_s += rs;  // per-lane partial; cross-quad combine deferred to epilogue

    // P^T -> Ps[q][kv] (per-wave slice; same-wave ds ordering handled by compiler)
#pragma unroll
    for (int mi = 0; mi < 4; mi++) {
      union { h16x2 h2[2]; uint2 u; } pk;
      pk.h2[0] = __builtin_amdgcn_cvt_pkrtz(sa[mi][0], sa[mi][1]);
      pk.h2[1] = __builtin_amdgcn_cvt_pkrtz(sa[mi][2], sa[mi][3]);
      *(uint2*)&Ps[w][l15 * 72 + mi * 16 + quad * 4] = pk.u;
    }

    // O^T += V^T P^T
#pragma unroll
    for (int kc2 = 0; kc2 < 2; kc2++) {
      f16x8 ap = *(const f16x8*)&Ps[w][l15 * 72 + kc2 * 32 + quad * 8];
#pragma unroll
      for (int ni = 0; ni < 4; ni++) {
        f16x8 vf =
            *(const f16x8*)&Vsh[buf][kc2 * 2048 + (ni * 16 + l15) * 32 + qsw * 8];
        oacc[ni] = __builtin_amdgcn_mfma_f32_16x16x32_f16(vf, ap, oacc[ni], 0, 0, 0);
      }
    }
  };

  // pair loop: stage 2 kv-tiles per barrier pair, then process both
  int kt = 0;
  while (kt + 1 <= qbB) {
    __syncthreads();
    stage(0, kt * 64);
    stage(1, kt * 64 + 64);
    __syncthreads();
    do_job(0, aqB, mB, lB, oB, qlaneB, kt * 64, false);
    if (kt <= qbA) do_job(0, aqA, mA, lA, oA, qlaneA, kt * 64, kt == qbA);
    do_job(1, aqB, mB, lB, oB, qlaneB, kt * 64 + 64, kt + 1 == qbB);
    if (kt + 1 <= qbA) do_job(1, aqA, mA, lA, oA, qlaneA, kt * 64 + 64, kt + 1 == qbA);
    kt += 2;
  }
  if (kt <= qbB) {  // odd tail tile
    __syncthreads();
    stage(0, kt * 64);
    __syncthreads();
    do_job(0, aqB, mB, lB, oB, qlaneB, kt * 64, kt == qbB);
    if (kt <= qbA) do_job(0, aqA, mA, lA, oA, qlaneA, kt * 64, kt == qbA);
  }

  // epilogue: combine per-lane l partials across the 4 quads of each q-row,
  // then normalize and write MH[b][q][h*64+v]; v = ni*16+quad*4+r
  {
    float lt = lB;
    lt += __shfl_xor(lt, 16);
    lt += __shfl_xor(lt, 32);
    float linv = 1.0f / lt;
    f16* dst = MH + ((size_t)b * S_ + qlaneB) * DM + h * DK + quad * 4;
#pragma unroll
    for (int ni = 0; ni < 4; ni++) {
      union { f16 hh[4]; uint2 u; } pk;
#pragma unroll
      for (int r = 0; r < 4; r++) pk.hh[r] = f2h(oB[ni][r] * linv);
      *(uint2*)(dst + ni * 16) = pk.u;
    }
  }
  {
    float lt = lA;
    lt += __shfl_xor(lt, 16);
    lt += __shfl_xor(lt, 32);
    float linv = 1.0f / lt;
    f16* dst = MH + ((size_t)b * S_ + qlaneA) * DM + h * DK + quad * 4;
#pragma unroll
    for (int ni = 0; ni < 4; ni++) {
      union { f16 hh[4]; uint2 u; } pk;
#pragma unroll
      for (int r = 0; r < 4; r++) pk.hh[r] = f2h(oA[ni][r] * linv);
      *(uint2*)(dst + ni * 16) = pk.u;
    }
  }
}

// ---------------- launch ----------------

extern "C" void kernel_launch(void* const* d_in, const int* in_sizes, int n_in,
                              void* d_out, int out_size, void* d_ws, size_t ws_size,
                              hipStream_t stream) {
  const float* residual = (const float*)d_in[0];
  const float* WQ = (const float*)d_in[1];
  const float* WK = (const float*)d_in[2];
  const float* WV = (const float*)d_in[3];
  const float* WO = (const float*)d_in[4];
  float* out = (float*)d_out;

  char* ws = (char*)d_ws;
  size_t off = 0;
  auto alloc = [&](size_t bytes) {
    void* p = ws + off;
    off += (bytes + 255) & ~(size_t)255;
    return p;
  };
  f16* xb = (f16*)alloc((size_t)B_ * S_ * DM * 2);   // 12.6 MB
  f16* wqkv = (f16*)alloc((size_t)3 * DM * DM * 2);  // 3.5 MB
  f16* wot = (f16*)alloc((size_t)DM * DM * 2);       // 1.2 MB
  f16* qk = (f16*)alloc(2 * HBSD * 2);               // 25.2 MB (Q,K)
  f16* vt = (f16*)alloc(HBSD * 2);                   // 12.6 MB (V^T)
  f16* mh = (f16*)alloc((size_t)B_ * S_ * DM * 2);   // 12.6 MB

  cast_x_kernel<<<(B_ * S_ * DM / 4 + 255) / 256, 256, 0, stream>>>(residual, xb,
                                                                    B_ * S_ * DM / 4);
  tcast_qkv_kernel<<<dim3(DM / 64, 3, H_), 256, 0, stream>>>(WQ, WK, WV, wqkv);
  tcast_wo_kernel<<<dim3(DM / 64, DM / 64), 256, 0, stream>>>(WO, wot);

  gemm_bt_kernel<1><<<dim3(3 * DM / 128, B_ * S_ / 128), 256, 0, stream>>>(
      xb, wqkv, nullptr, qk, vt, 3 * DM);

  flash_kernel<<<768, 256, 0, stream>>>(qk, qk + HBSD, vt, mh);

  gemm_bt_kernel<0><<<dim3(DM / 128, B_ * S_ / 128), 256, 0, stream>>>(
      mh, wot, out, nullptr, nullptr, DM);
}

// Round 7
// 211.918 us; speedup vs baseline: 1.0147x; 1.0147x over previous
//
#include <hip/hip_runtime.h>

typedef _Float16 f16;
typedef __fp16 h16x2 __attribute__((ext_vector_type(2)));
typedef _Float16 f16x8 __attribute__((ext_vector_type(8)));
typedef float f32x4 __attribute__((ext_vector_type(4)));

#define H_ 12
#define B_ 4
#define S_ 2048
#define DM 768
#define DK 64
#define HBSD ((size_t)H_ * B_ * S_ * DK)

__device__ __forceinline__ f16 f2h(float f) { return (f16)f; }
__device__ __forceinline__ float max3f(float a, float b, float c) {
  return fmaxf(fmaxf(a, b), c);  // clang fuses to v_max3_f32
}

// async global->LDS, 16B per lane. LDS dest must be wave-uniform base + lane*16.
__device__ __forceinline__ void gl_lds16(const f16* g, f16* l) {
  __builtin_amdgcn_global_load_lds(
      (const __attribute__((address_space(1))) void*)g,
      (__attribute__((address_space(3))) void*)l, 16, 0, 0);
}

// ---------------- prep kernels ----------------

__global__ __launch_bounds__(256) void cast_x_kernel(const float* __restrict__ x,
                                                     f16* __restrict__ xb, int n4) {
  int i = blockIdx.x * 256 + threadIdx.x;
  if (i < n4) {
    float4 v = ((const float4*)x)[i];
    union { f16 h[4]; uint2 u; } pk;
    pk.h[0] = f2h(v.x); pk.h[1] = f2h(v.y); pk.h[2] = f2h(v.z); pk.h[3] = f2h(v.w);
    ((uint2*)xb)[i] = pk.u;
  }
}

// Merged weight transpose+cast (one launch):
// which<3: W_{which}[h][m][c] -> Wt[(which*768 + h*64 + c)][m]
// which==3: WO[n][d] -> Wot[d][n]
__global__ __launch_bounds__(256) void tcast_w_kernel(const float* __restrict__ WQ,
                                                      const float* __restrict__ WK,
                                                      const float* __restrict__ WV,
                                                      const float* __restrict__ WO,
                                                      f16* __restrict__ Wt,
                                                      f16* __restrict__ Wot) {
  __shared__ float L[64][65];
  const int which = blockIdx.y;
  const int t = threadIdx.x;
  const int lr = t >> 2, lc = (t & 3) * 16;
  const float* ip;
  if (which < 3) {
    const int m0 = blockIdx.x * 64, h = blockIdx.z;
    const float* in = (which == 0 ? WQ : which == 1 ? WK : WV) + (size_t)h * DM * DK;
    ip = in + (size_t)(m0 + lr) * DK + lc;
  } else {
    const int n0 = blockIdx.x * 64, d0 = blockIdx.z * 64;
    ip = WO + (size_t)(n0 + lr) * DM + d0 + lc;
  }
#pragma unroll
  for (int i = 0; i < 4; i++) {
    float4 v = *(const float4*)(ip + i * 4);
    L[lr][lc + i * 4 + 0] = v.x;
    L[lr][lc + i * 4 + 1] = v.y;
    L[lr][lc + i * 4 + 2] = v.z;
    L[lr][lc + i * 4 + 3] = v.w;
  }
  __syncthreads();
  const int oc = t >> 2, om = (t & 3) * 16;
  union { f16 hh[16]; uint4 u[2]; } pk;
#pragma unroll
  for (int jx = 0; jx < 16; jx++) pk.hh[jx] = f2h(L[om + jx][oc]);
  f16* op;
  if (which < 3) {
    const int m0 = blockIdx.x * 64, h = blockIdx.z;
    op = Wt + ((size_t)which * DM + h * DK + oc) * DM + m0 + om;
  } else {
    const int n0 = blockIdx.x * 64, d0 = blockIdx.z * 64;
    op = Wot + (size_t)(d0 + oc) * DM + n0 + om;
  }
  *(uint4*)op = pk.u[0];
  *(uint4*)(op + 8) = pk.u[1];
}

// ---------------- GEMM, BK=64 2-slab: C[M,N] = A[M,K] * Bt[N,K]^T ----------------
// LDS layout per matrix: [slab s][row 128][32 cols]; slab stride 128*32 = 4096.
// Bank-conflict fix: XOR-swizzle byte bits 4-5 with row bits 1-2 (source-pre-swizzle
// + swizzled read quad qsw).
// XCD swizzle (T1): each XCD gets a contiguous chunk of the linear grid so A-row
// panels stay resident in its private L2 (nwg % 8 == 0 for both launches).
// Q outputs (MODE==1, which==0) are pre-scaled by log2(e)/8 so the flash kernel's
// QK^T scores come out directly in log2 units.
template <int MODE>
__global__ __launch_bounds__(256) void gemm_bt_kernel(const f16* __restrict__ A,
                                                      const f16* __restrict__ Bt,
                                                      float* __restrict__ Cf,
                                                      f16* __restrict__ Cq,
                                                      f16* __restrict__ Vt, int N) {
  constexpr int K = 768;
  __shared__ __align__(16) f16 As[2 * 128 * 32];
  __shared__ __align__(16) f16 Bs[2 * 128 * 32];
  const int t = threadIdx.x;
  const int nbx = gridDim.x, nwg = nbx * gridDim.y;
  const int d = blockIdx.y * nbx + blockIdx.x;
  const int wg = (d & 7) * (nwg >> 3) + (d >> 3);  // bijective (nwg%8==0)
  const int m0 = (wg / nbx) * 128, n0 = (wg % nbx) * 128;
  const int lane = t & 63, wave = t >> 6;
  const int l15 = lane & 15, quad = lane >> 4;
  const int qsw = quad ^ ((l15 >> 1) & 3);  // swizzled read quad
  const int m_off = (wave & 1) * 64, n_off = (wave >> 1) * 64;
  const int r0 = t >> 2, ko = ((t & 3) ^ ((t >> 3) & 3)) * 8;  // swizzled source col
  const f16* Ag0 = A + (size_t)(m0 + r0) * K + ko;
  const f16* Ag1 = A + (size_t)(m0 + r0 + 64) * K + ko;
  const f16* Bg0 = Bt + (size_t)(n0 + r0) * K + ko;
  const f16* Bg1 = Bt + (size_t)(n0 + r0 + 64) * K + ko;

  f32x4 acc[4][4];
  const f32x4 z4 = {0.f, 0.f, 0.f, 0.f};
  for (int i = 0; i < 4; i++)
    for (int j = 0; j < 4; j++) acc[i][j] = z4;

  for (int kt = 0; kt < K; kt += 64) {
    __syncthreads();
#pragma unroll
    for (int s = 0; s < 2; s++) {
      gl_lds16(Ag0 + kt + s * 32, &As[s * 4096 + t * 8]);
      gl_lds16(Ag1 + kt + s * 32, &As[s * 4096 + 2048 + t * 8]);
      gl_lds16(Bg0 + kt + s * 32, &Bs[s * 4096 + t * 8]);
      gl_lds16(Bg1 + kt + s * 32, &Bs[s * 4096 + 2048 + t * 8]);
    }
    __syncthreads();
#pragma unroll
    for (int s = 0; s < 2; s++) {
      f16x8 af[4], bfr[4];
#pragma unroll
      for (int i = 0; i < 4; i++)
        af[i] = *(const f16x8*)&As[s * 4096 + (m_off + i * 16 + l15) * 32 + qsw * 8];
#pragma unroll
      for (int i = 0; i < 4; i++)
        bfr[i] = *(const f16x8*)&Bs[s * 4096 + (n_off + i * 16 + l15) * 32 + qsw * 8];
#pragma unroll
      for (int mi = 0; mi < 4; mi++)
#pragma unroll
        for (int ni = 0; ni < 4; ni++)
          acc[mi][ni] = __builtin_amdgcn_mfma_f32_16x16x32_f16(af[mi], bfr[ni],
                                                               acc[mi][ni], 0, 0, 0);
    }
  }

  if (MODE == 0) {
#pragma unroll
    for (int mi = 0; mi < 4; mi++) {
      int row = m0 + m_off + mi * 16 + quad * 4;
#pragma unroll
      for (int ni = 0; ni < 4; ni++) {
        int col = n0 + n_off + ni * 16 + l15;
#pragma unroll
        for (int r = 0; r < 4; r++) Cf[(size_t)(row + r) * N + col] = acc[mi][ni][r];
      }
    }
  } else {
#pragma unroll
    for (int mi = 0; mi < 4; mi++) {
      int srow = m0 + m_off + mi * 16 + quad * 4;
      int bb = srow >> 11, ss = srow & 2047;
#pragma unroll
      for (int ni = 0; ni < 4; ni++) {
        int n = n0 + n_off + ni * 16 + l15;
        int which = n / DM;
        int rr = n - which * DM;
        int h = rr >> 6, kk = rr & 63;
        if (which < 2) {  // Q,K -> [h][b][s][64]; Q pre-scaled by log2(e)/8
          float scl = (which == 0) ? 0.18033688011f : 1.0f;
#pragma unroll
          for (int r = 0; r < 4; r++) {
            size_t dst = (size_t)which * HBSD +
                         ((size_t)((h * B_ + bb) * S_) + ss + r) * DK + kk;
            Cq[dst] = f2h(acc[mi][ni][r] * scl);
          }
        } else {  // V -> Vt [h][b][d][s]
          union { f16 hh[4]; uint2 u; } pk;
#pragma unroll
          for (int r = 0; r < 4; r++) pk.hh[r] = f2h(acc[mi][ni][r]);
          *(uint2*)&Vt[((size_t)(h * B_ + bb) * DK + kk) * S_ + ss] = pk.u;
        }
      }
    }
  }
}

// ---------------- flash attention v13: v12 + monotone-clamp fix ----------------
// 768 blocks; bid&7 = XCD; block owns q-tiles qbA=pr, qbB=31-pr of (h,b)=hb —
// 33 job-tiles per block. Pair-staging: 2 kv-tiles per barrier pair.
// v13: QK^T accumulator initialized to -m_s (bake running max into C-init; C/D
// col = l15 = q, so all 4 elements/lane share the column) — scores emerge
// max-shifted. Fast path: p = exp2(sa), 0 subs. Rescale path: shift mrc =
// max(mr, 0) — CLAMPED so m_s is monotone (v12 bug: rows whose tile max was
// below their running max got alpha = exp2(-mr) > 1 -> inf -> NaN).
__global__ __launch_bounds__(256, 3) void flash_kernel(const f16* __restrict__ Qg,
                                                       const f16* __restrict__ Kg,
                                                       const f16* __restrict__ Vtg,
                                                       f16* __restrict__ MH) {
  __shared__ __align__(16) f16 Ksh[2][4096];  // [tile][kc2][kv][32] (swizzled)
  __shared__ __align__(16) f16 Vsh[2][4096];  // [tile][kc2][v][32]  (swizzled)
  __shared__ __align__(16) f16 Ps[4][16 * 72];

  const int t = threadIdx.x, lane = t & 63, w = t >> 6;
  const int l15 = lane & 15, quad = lane >> 4;
  const int qsw = quad ^ ((l15 >> 1) & 3);  // swizzled read quad for Ksh/Vsh
  const int bid = blockIdx.x;
  const int xcd = bid & 7, gi = bid >> 3;
  const int hbi = gi % 6, pr = gi / 6;
  const int hb = xcd * 6 + hbi;
  const int qbA = pr, qbB = 31 - pr;
  const int h = hb >> 2, b = hb & 3;
  const size_t base = (size_t)hb * S_ * DK;
  const f16* Qp = Qg + base;
  const f16* Kp = Kg + base;
  const f16* Vp = Vtg + base;  // [d][S_]

  // Q fragments for both jobs, once from global (already ×log2(e)/8)
  f16x8 aqA[2], aqB[2];
  {
    const f16* qa = Qp + (size_t)(qbA * 64 + w * 16 + l15) * DK + quad * 8;
    aqA[0] = *(const f16x8*)(qa);
    aqA[1] = *(const f16x8*)(qa + 32);
    const f16* qb_ = Qp + (size_t)(qbB * 64 + w * 16 + l15) * DK + quad * 8;
    aqB[0] = *(const f16x8*)(qb_);
    aqB[1] = *(const f16x8*)(qb_ + 32);
  }
  const int qlaneA = qbA * 64 + w * 16 + l15;
  const int qlaneB = qbB * 64 + w * 16 + l15;

  // staging source: pre-swizzled column so linear global_load_lds yields the
  // swizzled LDS layout (both-sides-or-neither).
  const int srow = t >> 2, scol = ((t & 3) ^ ((t >> 3) & 3)) * 8;
  const f16* Kst = Kp + (size_t)srow * DK + scol;
  const f16* Vst = Vp + (size_t)srow * S_ + scol;

  float mA = -128.f, lA = 0.f, mB = -128.f, lB = 0.f;  // l is per-lane partial
  f32x4 oA[4], oB[4];
  const f32x4 z4 = {0.f, 0.f, 0.f, 0.f};
#pragma unroll
  for (int ni = 0; ni < 4; ni++) { oA[ni] = z4; oB[ni] = z4; }

  auto stage = [&](int buf, int kv0) {
    gl_lds16(Kst + (size_t)kv0 * DK, &Ksh[buf][t * 8]);
    gl_lds16(Kst + (size_t)kv0 * DK + 32, &Ksh[buf][2048 + t * 8]);
    gl_lds16(Vst + kv0, &Vsh[buf][t * 8]);
    gl_lds16(Vst + kv0 + 32, &Vsh[buf][2048 + t * 8]);
  };

  // per-job tile processing
  auto do_job = [&](int buf, const f16x8* aq, float& m_s, float& l_s, f32x4* oacc,
                    int qlane, int kv0, bool diag) {
    f32x4 sa[4];
    const f32x4 mC = {-m_s, -m_s, -m_s, -m_s};  // bake running max into C-init
#pragma unroll
    for (int mi = 0; mi < 4; mi++) {
      f16x8 k0 = *(const f16x8*)&Ksh[buf][(mi * 16 + l15) * 32 + qsw * 8];
      sa[mi] = __builtin_amdgcn_mfma_f32_16x16x32_f16(k0, aq[0], mC, 0, 0, 0);
    }
#pragma unroll
    for (int mi = 0; mi < 4; mi++) {
      f16x8 k1 = *(const f16x8*)&Ksh[buf][2048 + (mi * 16 + l15) * 32 + qsw * 8];
      sa[mi] = __builtin_amdgcn_mfma_f32_16x16x32_f16(k1, aq[1], sa[mi], 0, 0, 0);
    }

    if (diag) {  // diagonal tile: mask kv > q
#pragma unroll
      for (int mi = 0; mi < 4; mi++)
#pragma unroll
        for (int r = 0; r < 4; r++)
          if (kv0 + mi * 16 + quad * 4 + r > qlane) sa[mi][r] = -1e30f;
    }

    // per-lane max of this lane's 16 max-shifted scores
    float g0 = max3f(sa[0][0], sa[0][1], sa[0][2]);
    float g1 = max3f(sa[0][3], sa[1][0], sa[1][1]);
    float g2 = max3f(sa[1][2], sa[1][3], sa[2][0]);
    float g3 = max3f(sa[2][1], sa[2][2], sa[2][3]);
    float g4 = max3f(sa[3][0], sa[3][1], sa[3][2]);
    float mx = fmaxf(max3f(g0, g1, g2), max3f(g3, g4, sa[3][3]));
    float rs = 0.f;
    // defer-max (T13): fast path = no cross-lane reduce, no subs, m unchanged.
    if (!__all(mx <= 8.f)) {
      // form row max (4 quads share a q-row); clamp shift to keep m monotone
      float mr = fmaxf(mx, __shfl_xor(mx, 16));
      mr = fmaxf(mr, __shfl_xor(mr, 32));
      float mrc = fmaxf(mr, 0.f);  // rows below their running max: identity
      float alpha = __builtin_exp2f(-mrc);
      l_s *= alpha;
#pragma unroll
      for (int ni = 0; ni < 4; ni++)
#pragma unroll
        for (int r = 0; r < 4; r++) oacc[ni][r] *= alpha;
      m_s += mrc;
#pragma unroll
      for (int mi = 0; mi < 4; mi++)
#pragma unroll
        for (int r = 0; r < 4; r++) {
          float p = __builtin_exp2f(sa[mi][r] - mrc);
          sa[mi][r] = p;
          rs += p;
        }
    } else {
#pragma unroll
      for (int mi = 0; mi < 4; mi++)
#pragma unroll
        for (int r = 0; r < 4; r++) {
          float p = __builtin_exp2f(sa[mi][r]);
          sa[mi][r] = p;
          rs += p;
        }
    }
    l_s += rs;  // per-lane partial; cross-quad combine deferred to epilogue

    // P^T -> Ps[q][kv] (per-wave slice; same-wave ds ordering handled by compiler)
#pragma unroll
    for (int mi = 0; mi < 4; mi++) {
      union { h16x2 h2[2]; uint2 u; } pk;
      pk.h2[0] = __builtin_amdgcn_cvt_pkrtz(sa[mi][0], sa[mi][1]);
      pk.h2[1] = __builtin_amdgcn_cvt_pkrtz(sa[mi][2], sa[mi][3]);
      *(uint2*)&Ps[w][l15 * 72 + mi * 16 + quad * 4] = pk.u;
    }

    // O^T += V^T P^T
#pragma unroll
    for (int kc2 = 0; kc2 < 2; kc2++) {
      f16x8 ap = *(const f16x8*)&Ps[w][l15 * 72 + kc2 * 32 + quad * 8];
#pragma unroll
      for (int ni = 0; ni < 4; ni++) {
        f16x8 vf =
            *(const f16x8*)&Vsh[buf][kc2 * 2048 + (ni * 16 + l15) * 32 + qsw * 8];
        oacc[ni] = __builtin_amdgcn_mfma_f32_16x16x32_f16(vf, ap, oacc[ni], 0, 0, 0);
      }
    }
  };

  // pair loop: stage 2 kv-tiles per barrier pair, then process both
  int kt = 0;
  while (kt + 1 <= qbB) {
    __syncthreads();
    stage(0, kt * 64);
    stage(1, kt * 64 + 64);
    __syncthreads();
    do_job(0, aqB, mB, lB, oB, qlaneB, kt * 64, false);
    if (kt <= qbA) do_job(0, aqA, mA, lA, oA, qlaneA, kt * 64, kt == qbA);
    do_job(1, aqB, mB, lB, oB, qlaneB, kt * 64 + 64, kt + 1 == qbB);
    if (kt + 1 <= qbA) do_job(1, aqA, mA, lA, oA, qlaneA, kt * 64 + 64, kt + 1 == qbA);
    kt += 2;
  }
  if (kt <= qbB) {  // odd tail tile
    __syncthreads();
    stage(0, kt * 64);
    __syncthreads();
    do_job(0, aqB, mB, lB, oB, qlaneB, kt * 64, kt == qbB);
    if (kt <= qbA) do_job(0, aqA, mA, lA, oA, qlaneA, kt * 64, kt == qbA);
  }

  // epilogue: combine per-lane l partials across the 4 quads of each q-row,
  // then normalize and write MH[b][q][h*64+v]; v = ni*16+quad*4+r
  {
    float lt = lB;
    lt += __shfl_xor(lt, 16);
    lt += __shfl_xor(lt, 32);
    float linv = 1.0f / lt;
    f16* dst = MH + ((size_t)b * S_ + qlaneB) * DM + h * DK + quad * 4;
#pragma unroll
    for (int ni = 0; ni < 4; ni++) {
      union { f16 hh[4]; uint2 u; } pk;
#pragma unroll
      for (int r = 0; r < 4; r++) pk.hh[r] = f2h(oB[ni][r] * linv);
      *(uint2*)(dst + ni * 16) = pk.u;
    }
  }
  {
    float lt = lA;
    lt += __shfl_xor(lt, 16);
    lt += __shfl_xor(lt, 32);
    float linv = 1.0f / lt;
    f16* dst = MH + ((size_t)b * S_ + qlaneA) * DM + h * DK + quad * 4;
#pragma unroll
    for (int ni = 0; ni < 4; ni++) {
      union { f16 hh[4]; uint2 u; } pk;
#pragma unroll
      for (int r = 0; r < 4; r++) pk.hh[r] = f2h(oA[ni][r] * linv);
      *(uint2*)(dst + ni * 16) = pk.u;
    }
  }
}

// ---------------- launch ----------------

extern "C" void kernel_launch(void* const* d_in, const int* in_sizes, int n_in,
                              void* d_out, int out_size, void* d_ws, size_t ws_size,
                              hipStream_t stream) {
  const float* residual = (const float*)d_in[0];
  const float* WQ = (const float*)d_in[1];
  const float* WK = (const float*)d_in[2];
  const float* WV = (const float*)d_in[3];
  const float* WO = (const float*)d_in[4];
  float* out = (float*)d_out;

  char* ws = (char*)d_ws;
  size_t off = 0;
  auto alloc = [&](size_t bytes) {
    void* p = ws + off;
    off += (bytes + 255) & ~(size_t)255;
    return p;
  };
  f16* xb = (f16*)alloc((size_t)B_ * S_ * DM * 2);   // 12.6 MB
  f16* wqkv = (f16*)alloc((size_t)3 * DM * DM * 2);  // 3.5 MB
  f16* wot = (f16*)alloc((size_t)DM * DM * 2);       // 1.2 MB
  f16* qk = (f16*)alloc(2 * HBSD * 2);               // 25.2 MB (Q,K)
  f16* vt = (f16*)alloc(HBSD * 2);                   // 12.6 MB (V^T)
  f16* mh = (f16*)alloc((size_t)B_ * S_ * DM * 2);   // 12.6 MB

  cast_x_kernel<<<(B_ * S_ * DM / 4 + 255) / 256, 256, 0, stream>>>(residual, xb,
                                                                    B_ * S_ * DM / 4);
  tcast_w_kernel<<<dim3(DM / 64, 4, H_), 256, 0, stream>>>(WQ, WK, WV, WO, wqkv, wot);

  gemm_bt_kernel<1><<<dim3(3 * DM / 128, B_ * S_ / 128), 256, 0, stream>>>(
      xb, wqkv, nullptr, qk, vt, 3 * DM);

  flash_kernel<<<768, 256, 0, stream>>>(qk, qk + HBSD, vt, mh);

  gemm_bt_kernel<0><<<dim3(DM / 128, B_ * S_ / 128), 256, 0, stream>>>(
      mh, wot, out, nullptr, nullptr, DM);
}

// Round 8
// 206.018 us; speedup vs baseline: 1.0437x; 1.0286x over previous
//
#include <hip/hip_runtime.h>

typedef _Float16 f16;
typedef __fp16 h16x2 __attribute__((ext_vector_type(2)));
typedef _Float16 f16x8 __attribute__((ext_vector_type(8)));
typedef float f32x4 __attribute__((ext_vector_type(4)));

#define H_ 12
#define B_ 4
#define S_ 2048
#define DM 768
#define DK 64
#define HBSD ((size_t)H_ * B_ * S_ * DK)

__device__ __forceinline__ f16 f2h(float f) { return (f16)f; }
__device__ __forceinline__ float max3f(float a, float b, float c) {
  return fmaxf(fmaxf(a, b), c);  // clang fuses to v_max3_f32
}

// async global->LDS, 16B per lane. LDS dest must be wave-uniform base + lane*16.
__device__ __forceinline__ void gl_lds16(const f16* g, f16* l) {
  __builtin_amdgcn_global_load_lds(
      (const __attribute__((address_space(1))) void*)g,
      (__attribute__((address_space(3))) void*)l, 16, 0, 0);
}

// ---------------- prep kernels ----------------

__global__ __launch_bounds__(256) void cast_x_kernel(const float* __restrict__ x,
                                                     f16* __restrict__ xb, int n4) {
  int i = blockIdx.x * 256 + threadIdx.x;
  if (i < n4) {
    float4 v = ((const float4*)x)[i];
    union { f16 h[4]; uint2 u; } pk;
    pk.h[0] = f2h(v.x); pk.h[1] = f2h(v.y); pk.h[2] = f2h(v.z); pk.h[3] = f2h(v.w);
    ((uint2*)xb)[i] = pk.u;
  }
}

// Merged weight transpose+cast (one launch):
// which<3: W_{which}[h][m][c] -> Wt[(which*768 + h*64 + c)][m]
// which==3: WO[n][d] -> Wot[d][n]
__global__ __launch_bounds__(256) void tcast_w_kernel(const float* __restrict__ WQ,
                                                      const float* __restrict__ WK,
                                                      const float* __restrict__ WV,
                                                      const float* __restrict__ WO,
                                                      f16* __restrict__ Wt,
                                                      f16* __restrict__ Wot) {
  __shared__ float L[64][65];
  const int which = blockIdx.y;
  const int t = threadIdx.x;
  const int lr = t >> 2, lc = (t & 3) * 16;
  const float* ip;
  if (which < 3) {
    const int m0 = blockIdx.x * 64, h = blockIdx.z;
    const float* in = (which == 0 ? WQ : which == 1 ? WK : WV) + (size_t)h * DM * DK;
    ip = in + (size_t)(m0 + lr) * DK + lc;
  } else {
    const int n0 = blockIdx.x * 64, d0 = blockIdx.z * 64;
    ip = WO + (size_t)(n0 + lr) * DM + d0 + lc;
  }
#pragma unroll
  for (int i = 0; i < 4; i++) {
    float4 v = *(const float4*)(ip + i * 4);
    L[lr][lc + i * 4 + 0] = v.x;
    L[lr][lc + i * 4 + 1] = v.y;
    L[lr][lc + i * 4 + 2] = v.z;
    L[lr][lc + i * 4 + 3] = v.w;
  }
  __syncthreads();
  const int oc = t >> 2, om = (t & 3) * 16;
  union { f16 hh[16]; uint4 u[2]; } pk;
#pragma unroll
  for (int jx = 0; jx < 16; jx++) pk.hh[jx] = f2h(L[om + jx][oc]);
  f16* op;
  if (which < 3) {
    const int m0 = blockIdx.x * 64, h = blockIdx.z;
    op = Wt + ((size_t)which * DM + h * DK + oc) * DM + m0 + om;
  } else {
    const int n0 = blockIdx.x * 64, d0 = blockIdx.z * 64;
    op = Wot + (size_t)(d0 + oc) * DM + n0 + om;
  }
  *(uint4*)op = pk.u[0];
  *(uint4*)(op + 8) = pk.u[1];
}

// ---------------- GEMM, BK=64 2-slab: C[M,N] = A[M,K] * Bt[N,K]^T ----------------
// LDS layout per matrix: [slab s][row 128][32 cols]; slab stride 128*32 = 4096.
// Bank-conflict fix: XOR-swizzle byte bits 4-5 with row bits 1-2 (source-pre-swizzle
// + swizzled read quad qsw). XCD swizzle (T1) for L2 locality.
// Q outputs pre-scaled by log2(e)/8.
// v14: V blocks (n0 >= 1536; block col-ranges are pure Q/K/V since 768%128==0)
// write V^T via an LDS transpose reusing the 32KB staging buffer — the old path
// was an 8B-per-4KB-stride scatter (8x HBM write amplification, ~100MB traffic).
template <int MODE>
__global__ __launch_bounds__(256) void gemm_bt_kernel(const f16* __restrict__ A,
                                                      const f16* __restrict__ Bt,
                                                      float* __restrict__ Cf,
                                                      f16* __restrict__ Cq,
                                                      f16* __restrict__ Vt, int N) {
  constexpr int K = 768;
  __shared__ __align__(16) f16 SH[16384];  // As | Bs; reused as V-transpose buffer
  f16* As = SH;
  f16* Bs = SH + 8192;
  const int t = threadIdx.x;
  const int nbx = gridDim.x, nwg = nbx * gridDim.y;
  const int d = blockIdx.y * nbx + blockIdx.x;
  const int wg = (d & 7) * (nwg >> 3) + (d >> 3);  // bijective (nwg%8==0)
  const int m0 = (wg / nbx) * 128, n0 = (wg % nbx) * 128;
  const int lane = t & 63, wave = t >> 6;
  const int l15 = lane & 15, quad = lane >> 4;
  const int qsw = quad ^ ((l15 >> 1) & 3);  // swizzled read quad
  const int m_off = (wave & 1) * 64, n_off = (wave >> 1) * 64;
  const int r0 = t >> 2, ko = ((t & 3) ^ ((t >> 3) & 3)) * 8;  // swizzled source col
  const f16* Ag0 = A + (size_t)(m0 + r0) * K + ko;
  const f16* Ag1 = A + (size_t)(m0 + r0 + 64) * K + ko;
  const f16* Bg0 = Bt + (size_t)(n0 + r0) * K + ko;
  const f16* Bg1 = Bt + (size_t)(n0 + r0 + 64) * K + ko;

  f32x4 acc[4][4];
  const f32x4 z4 = {0.f, 0.f, 0.f, 0.f};
  for (int i = 0; i < 4; i++)
    for (int j = 0; j < 4; j++) acc[i][j] = z4;

  for (int kt = 0; kt < K; kt += 64) {
    __syncthreads();
#pragma unroll
    for (int s = 0; s < 2; s++) {
      gl_lds16(Ag0 + kt + s * 32, &As[s * 4096 + t * 8]);
      gl_lds16(Ag1 + kt + s * 32, &As[s * 4096 + 2048 + t * 8]);
      gl_lds16(Bg0 + kt + s * 32, &Bs[s * 4096 + t * 8]);
      gl_lds16(Bg1 + kt + s * 32, &Bs[s * 4096 + 2048 + t * 8]);
    }
    __syncthreads();
#pragma unroll
    for (int s = 0; s < 2; s++) {
      f16x8 af[4], bfr[4];
#pragma unroll
      for (int i = 0; i < 4; i++)
        af[i] = *(const f16x8*)&As[s * 4096 + (m_off + i * 16 + l15) * 32 + qsw * 8];
#pragma unroll
      for (int i = 0; i < 4; i++)
        bfr[i] = *(const f16x8*)&Bs[s * 4096 + (n_off + i * 16 + l15) * 32 + qsw * 8];
#pragma unroll
      for (int mi = 0; mi < 4; mi++)
#pragma unroll
        for (int ni = 0; ni < 4; ni++)
          acc[mi][ni] = __builtin_amdgcn_mfma_f32_16x16x32_f16(af[mi], bfr[ni],
                                                               acc[mi][ni], 0, 0, 0);
    }
  }

  if (MODE == 0) {
#pragma unroll
    for (int mi = 0; mi < 4; mi++) {
      int row = m0 + m_off + mi * 16 + quad * 4;
#pragma unroll
      for (int ni = 0; ni < 4; ni++) {
        int col = n0 + n_off + ni * 16 + l15;
#pragma unroll
        for (int r = 0; r < 4; r++) Cf[(size_t)(row + r) * N + col] = acc[mi][ni][r];
      }
    }
  } else {
    if (n0 < 2 * DM) {  // Q or K block (uniform 'which' per block: 768%128==0)
      const int which = n0 / DM;
      const float scl = (which == 0) ? 0.18033688011f : 1.0f;
#pragma unroll
      for (int mi = 0; mi < 4; mi++) {
        int srow = m0 + m_off + mi * 16 + quad * 4;
        int bb = srow >> 11, ss = srow & 2047;
#pragma unroll
        for (int ni = 0; ni < 4; ni++) {
          int n = n0 + n_off + ni * 16 + l15;
          int rr = n - which * DM;
          int h = rr >> 6, kk = rr & 63;
#pragma unroll
          for (int r = 0; r < 4; r++) {
            size_t dst = (size_t)which * HBSD +
                         ((size_t)((h * B_ + bb) * S_) + ss + r) * DK + kk;
            Cq[dst] = f2h(acc[mi][ni][r] * scl);
          }
        }
      }
    } else {  // V block: coalesced V^T via LDS transpose (reuse SH)
      __syncthreads();  // all waves done with As/Bs reads
#pragma unroll
      for (int mi = 0; mi < 4; mi++) {
        int ssb = m_off + mi * 16 + quad * 4;
#pragma unroll
        for (int ni = 0; ni < 4; ni++) {
          int c = n_off + ni * 16 + l15;
          f16* row = &SH[c * 128];
          int swz = (c & 7) << 3;  // XOR ss bits 3-5: spreads the 256B-stride banks
#pragma unroll
          for (int r = 0; r < 4; r++) row[(ssb + r) ^ swz] = f2h(acc[mi][ni][r]);
        }
      }
      __syncthreads();
      const int bb = m0 >> 11, ssbase = m0 & 2047;
      const int hbase = (n0 - 2 * DM) >> 6;
      const int l15t = t & 15, rowg = t >> 4;
#pragma unroll
      for (int j = 0; j < 8; j++) {
        int c = rowg + 16 * j;  // 0..127
        int h2 = hbase + (c >> 6), kk = c & 63;
        f16x8 v = *(const f16x8*)&SH[c * 128 + ((l15t * 8) ^ ((c & 7) << 3))];
        *(f16x8*)&Vt[((size_t)(h2 * B_ + bb) * DK + kk) * S_ + ssbase + l15t * 8] = v;
      }
    }
  }
}

// ---------------- flash attention v13: pair-staging + C-init max-bake ----------
// 768 blocks; bid&7 = XCD; block owns q-tiles qbA=pr, qbB=31-pr of (h,b)=hb —
// 33 job-tiles per block. Pair-staging: 2 kv-tiles per barrier pair.
// QK^T accumulator initialized to -m_s; fast path p = exp2(sa); rescale shift
// clamped non-negative (monotone m).
__global__ __launch_bounds__(256, 3) void flash_kernel(const f16* __restrict__ Qg,
                                                       const f16* __restrict__ Kg,
                                                       const f16* __restrict__ Vtg,
                                                       f16* __restrict__ MH) {
  __shared__ __align__(16) f16 Ksh[2][4096];  // [tile][kc2][kv][32] (swizzled)
  __shared__ __align__(16) f16 Vsh[2][4096];  // [tile][kc2][v][32]  (swizzled)
  __shared__ __align__(16) f16 Ps[4][16 * 72];

  const int t = threadIdx.x, lane = t & 63, w = t >> 6;
  const int l15 = lane & 15, quad = lane >> 4;
  const int qsw = quad ^ ((l15 >> 1) & 3);  // swizzled read quad for Ksh/Vsh
  const int bid = blockIdx.x;
  const int xcd = bid & 7, gi = bid >> 3;
  const int hbi = gi % 6, pr = gi / 6;
  const int hb = xcd * 6 + hbi;
  const int qbA = pr, qbB = 31 - pr;
  const int h = hb >> 2, b = hb & 3;
  const size_t base = (size_t)hb * S_ * DK;
  const f16* Qp = Qg + base;
  const f16* Kp = Kg + base;
  const f16* Vp = Vtg + base;  // [d][S_]

  // Q fragments for both jobs, once from global (already ×log2(e)/8)
  f16x8 aqA[2], aqB[2];
  {
    const f16* qa = Qp + (size_t)(qbA * 64 + w * 16 + l15) * DK + quad * 8;
    aqA[0] = *(const f16x8*)(qa);
    aqA[1] = *(const f16x8*)(qa + 32);
    const f16* qb_ = Qp + (size_t)(qbB * 64 + w * 16 + l15) * DK + quad * 8;
    aqB[0] = *(const f16x8*)(qb_);
    aqB[1] = *(const f16x8*)(qb_ + 32);
  }
  const int qlaneA = qbA * 64 + w * 16 + l15;
  const int qlaneB = qbB * 64 + w * 16 + l15;

  // staging source: pre-swizzled column so linear global_load_lds yields the
  // swizzled LDS layout (both-sides-or-neither).
  const int srow = t >> 2, scol = ((t & 3) ^ ((t >> 3) & 3)) * 8;
  const f16* Kst = Kp + (size_t)srow * DK + scol;
  const f16* Vst = Vp + (size_t)srow * S_ + scol;

  float mA = -128.f, lA = 0.f, mB = -128.f, lB = 0.f;  // l is per-lane partial
  f32x4 oA[4], oB[4];
  const f32x4 z4 = {0.f, 0.f, 0.f, 0.f};
#pragma unroll
  for (int ni = 0; ni < 4; ni++) { oA[ni] = z4; oB[ni] = z4; }

  auto stage = [&](int buf, int kv0) {
    gl_lds16(Kst + (size_t)kv0 * DK, &Ksh[buf][t * 8]);
    gl_lds16(Kst + (size_t)kv0 * DK + 32, &Ksh[buf][2048 + t * 8]);
    gl_lds16(Vst + kv0, &Vsh[buf][t * 8]);
    gl_lds16(Vst + kv0 + 32, &Vsh[buf][2048 + t * 8]);
  };

  // per-job tile processing
  auto do_job = [&](int buf, const f16x8* aq, float& m_s, float& l_s, f32x4* oacc,
                    int qlane, int kv0, bool diag) {
    f32x4 sa[4];
    const f32x4 mC = {-m_s, -m_s, -m_s, -m_s};  // bake running max into C-init
#pragma unroll
    for (int mi = 0; mi < 4; mi++) {
      f16x8 k0 = *(const f16x8*)&Ksh[buf][(mi * 16 + l15) * 32 + qsw * 8];
      sa[mi] = __builtin_amdgcn_mfma_f32_16x16x32_f16(k0, aq[0], mC, 0, 0, 0);
    }
#pragma unroll
    for (int mi = 0; mi < 4; mi++) {
      f16x8 k1 = *(const f16x8*)&Ksh[buf][2048 + (mi * 16 + l15) * 32 + qsw * 8];
      sa[mi] = __builtin_amdgcn_mfma_f32_16x16x32_f16(k1, aq[1], sa[mi], 0, 0, 0);
    }

    if (diag) {  // diagonal tile: mask kv > q
#pragma unroll
      for (int mi = 0; mi < 4; mi++)
#pragma unroll
        for (int r = 0; r < 4; r++)
          if (kv0 + mi * 16 + quad * 4 + r > qlane) sa[mi][r] = -1e30f;
    }

    // per-lane max of this lane's 16 max-shifted scores
    float g0 = max3f(sa[0][0], sa[0][1], sa[0][2]);
    float g1 = max3f(sa[0][3], sa[1][0], sa[1][1]);
    float g2 = max3f(sa[1][2], sa[1][3], sa[2][0]);
    float g3 = max3f(sa[2][1], sa[2][2], sa[2][3]);
    float g4 = max3f(sa[3][0], sa[3][1], sa[3][2]);
    float mx = fmaxf(max3f(g0, g1, g2), max3f(g3, g4, sa[3][3]));
    float rs = 0.f;
    // defer-max (T13): fast path = no cross-lane reduce, no subs, m unchanged.
    if (!__all(mx <= 8.f)) {
      // form row max (4 quads share a q-row); clamp shift to keep m monotone
      float mr = fmaxf(mx, __shfl_xor(mx, 16));
      mr = fmaxf(mr, __shfl_xor(mr, 32));
      float mrc = fmaxf(mr, 0.f);  // rows below their running max: identity
      float alpha = __builtin_exp2f(-mrc);
      l_s *= alpha;
#pragma unroll
      for (int ni = 0; ni < 4; ni++)
#pragma unroll
        for (int r = 0; r < 4; r++) oacc[ni][r] *= alpha;
      m_s += mrc;
#pragma unroll
      for (int mi = 0; mi < 4; mi++)
#pragma unroll
        for (int r = 0; r < 4; r++) {
          float p = __builtin_exp2f(sa[mi][r] - mrc);
          sa[mi][r] = p;
          rs += p;
        }
    } else {
#pragma unroll
      for (int mi = 0; mi < 4; mi++)
#pragma unroll
        for (int r = 0; r < 4; r++) {
          float p = __builtin_exp2f(sa[mi][r]);
          sa[mi][r] = p;
          rs += p;
        }
    }
    l_s += rs;  // per-lane partial; cross-quad combine deferred to epilogue

    // P^T -> Ps[q][kv] (per-wave slice; same-wave ds ordering handled by compiler)
#pragma unroll
    for (int mi = 0; mi < 4; mi++) {
      union { h16x2 h2[2]; uint2 u; } pk;
      pk.h2[0] = __builtin_amdgcn_cvt_pkrtz(sa[mi][0], sa[mi][1]);
      pk.h2[1] = __builtin_amdgcn_cvt_pkrtz(sa[mi][2], sa[mi][3]);
      *(uint2*)&Ps[w][l15 * 72 + mi * 16 + quad * 4] = pk.u;
    }

    // O^T += V^T P^T
#pragma unroll
    for (int kc2 = 0; kc2 < 2; kc2++) {
      f16x8 ap = *(const f16x8*)&Ps[w][l15 * 72 + kc2 * 32 + quad * 8];
#pragma unroll
      for (int ni = 0; ni < 4; ni++) {
        f16x8 vf =
            *(const f16x8*)&Vsh[buf][kc2 * 2048 + (ni * 16 + l15) * 32 + qsw * 8];
        oacc[ni] = __builtin_amdgcn_mfma_f32_16x16x32_f16(vf, ap, oacc[ni], 0, 0, 0);
      }
    }
  };

  // pair loop: stage 2 kv-tiles per barrier pair, then process both
  int kt = 0;
  while (kt + 1 <= qbB) {
    __syncthreads();
    stage(0, kt * 64);
    stage(1, kt * 64 + 64);
    __syncthreads();
    do_job(0, aqB, mB, lB, oB, qlaneB, kt * 64, false);
    if (kt <= qbA) do_job(0, aqA, mA, lA, oA, qlaneA, kt * 64, kt == qbA);
    do_job(1, aqB, mB, lB, oB, qlaneB, kt * 64 + 64, kt + 1 == qbB);
    if (kt + 1 <= qbA) do_job(1, aqA, mA, lA, oA, qlaneA, kt * 64 + 64, kt + 1 == qbA);
    kt += 2;
  }
  if (kt <= qbB) {  // odd tail tile
    __syncthreads();
    stage(0, kt * 64);
    __syncthreads();
    do_job(0, aqB, mB, lB, oB, qlaneB, kt * 64, kt == qbB);
    if (kt <= qbA) do_job(0, aqA, mA, lA, oA, qlaneA, kt * 64, kt == qbA);
  }

  // epilogue: combine per-lane l partials across the 4 quads of each q-row,
  // then normalize and write MH[b][q][h*64+v]; v = ni*16+quad*4+r
  {
    float lt = lB;
    lt += __shfl_xor(lt, 16);
    lt += __shfl_xor(lt, 32);
    float linv = 1.0f / lt;
    f16* dst = MH + ((size_t)b * S_ + qlaneB) * DM + h * DK + quad * 4;
#pragma unroll
    for (int ni = 0; ni < 4; ni++) {
      union { f16 hh[4]; uint2 u; } pk;
#pragma unroll
      for (int r = 0; r < 4; r++) pk.hh[r] = f2h(oB[ni][r] * linv);
      *(uint2*)(dst + ni * 16) = pk.u;
    }
  }
  {
    float lt = lA;
    lt += __shfl_xor(lt, 16);
    lt += __shfl_xor(lt, 32);
    float linv = 1.0f / lt;
    f16* dst = MH + ((size_t)b * S_ + qlaneA) * DM + h * DK + quad * 4;
#pragma unroll
    for (int ni = 0; ni < 4; ni++) {
      union { f16 hh[4]; uint2 u; } pk;
#pragma unroll
      for (int r = 0; r < 4; r++) pk.hh[r] = f2h(oA[ni][r] * linv);
      *(uint2*)(dst + ni * 16) = pk.u;
    }
  }
}

// ---------------- launch ----------------

extern "C" void kernel_launch(void* const* d_in, const int* in_sizes, int n_in,
                              void* d_out, int out_size, void* d_ws, size_t ws_size,
                              hipStream_t stream) {
  const float* residual = (const float*)d_in[0];
  const float* WQ = (const float*)d_in[1];
  const float* WK = (const float*)d_in[2];
  const float* WV = (const float*)d_in[3];
  const float* WO = (const float*)d_in[4];
  float* out = (float*)d_out;

  char* ws = (char*)d_ws;
  size_t off = 0;
  auto alloc = [&](size_t bytes) {
    void* p = ws + off;
    off += (bytes + 255) & ~(size_t)255;
    return p;
  };
  f16* xb = (f16*)alloc((size_t)B_ * S_ * DM * 2);   // 12.6 MB
  f16* wqkv = (f16*)alloc((size_t)3 * DM * DM * 2);  // 3.5 MB
  f16* wot = (f16*)alloc((size_t)DM * DM * 2);       // 1.2 MB
  f16* qk = (f16*)alloc(2 * HBSD * 2);               // 25.2 MB (Q,K)
  f16* vt = (f16*)alloc(HBSD * 2);                   // 12.6 MB (V^T)
  f16* mh = (f16*)alloc((size_t)B_ * S_ * DM * 2);   // 12.6 MB

  cast_x_kernel<<<(B_ * S_ * DM / 4 + 255) / 256, 256, 0, stream>>>(residual, xb,
                                                                    B_ * S_ * DM / 4);
  tcast_w_kernel<<<dim3(DM / 64, 4, H_), 256, 0, stream>>>(WQ, WK, WV, WO, wqkv, wot);

  gemm_bt_kernel<1><<<dim3(3 * DM / 128, B_ * S_ / 128), 256, 0, stream>>>(
      xb, wqkv, nullptr, qk, vt, 3 * DM);

  flash_kernel<<<768, 256, 0, stream>>>(qk, qk + HBSD, vt, mh);

  gemm_bt_kernel<0><<<dim3(DM / 128, B_ * S_ / 128), 256, 0, stream>>>(
      mh, wot, out, nullptr, nullptr, DM);
}